// Round 2
// baseline (213.913 us; speedup 1.0000x reference)
//
#include <hip/hip_runtime.h>
#include <math.h>

// Problem constants
#define BB   1024
#define MM   32
#define NN   64
#define DD   32
#define NOBJ 20
#define NV   6890
#define KK   6144      // M*N*3
#define JJ   192       // N*3

// Kernel 1: reduce pca_components / pca_means over m (sum of M=32 strided rows).
// Cred[o*D*192 + d*192 + j] = sum_m comps[o][d][m*192 + j]
// Mred[o*192 + j]           = sum_m means[o][m*192 + j]
__global__ void reduce_pca(const float* __restrict__ comps,
                           const float* __restrict__ means,
                           float* __restrict__ Cred,
                           float* __restrict__ Mred) {
    int t = blockIdx.x * blockDim.x + threadIdx.x;
    const int NC = NOBJ * DD * JJ;           // 122880
    if (t < NC) {
        int j  = t % JJ;
        int od = t / JJ;                     // o*D + d
        const float* p = comps + (size_t)od * KK + j;
        float s = 0.f;
#pragma unroll
        for (int m = 0; m < MM; ++m) s += p[m * JJ];
        Cred[t] = s;
    } else {
        int t2 = t - NC;
        if (t2 < NOBJ * JJ) {
            int j = t2 % JJ;
            int o = t2 / JJ;
            const float* p = means + (size_t)o * KK + j;
            float s = 0.f;
#pragma unroll
            for (int m = 0; m < MM; ++m) s += p[m * JJ];
            Mred[t2] = s;
        }
    }
}

// Kernel 2: one block (192 threads) per batch element.
__global__ __launch_bounds__(192) void per_batch(
    const float* __restrict__ gamma,    // [B,32]
    const float* __restrict__ smpl_v,   // [B,NV,3]
    const float* __restrict__ oanch,    // [NOBJ,64,3]
    const int*   __restrict__ labels,   // [B]
    const int*   __restrict__ sidx,     // [32]
    const float* __restrict__ Cred,     // [NOBJ, D, 192]
    const float* __restrict__ Mred,     // [NOBJ, 192]
    float* __restrict__ out)            // R flat [B*9] then T flat [B*3]
{
    const int b   = blockIdx.x;
    const int tid = threadIdx.x;

    __shared__ float s_gamma[DD];
    __shared__ float s_oa[JJ];
    __shared__ float s_off[JJ];
    __shared__ float s_sa[MM * 3];
    __shared__ float s_SA[3], s_c[3], s_sumoff[3];
    __shared__ float s_H[9];

    const int o = labels[b];

    if (tid < DD) s_gamma[tid] = gamma[b * DD + tid];
    if (tid < MM * 3) {
        int m = tid / 3, i = tid % 3;
        int v = sidx[m];
        s_sa[tid] = smpl_v[((size_t)b * NV + v) * 3 + i];
    }
    s_oa[tid] = oanch[o * JJ + tid];    // blockDim == 192 == JJ
    __syncthreads();

    // OffSum[j] = Mred[o][j] + sum_d Cred[o][d][j] * gamma[d]
    {
        float acc = Mred[o * JJ + tid];
        const float* cp = Cred + (size_t)o * DD * JJ + tid;
#pragma unroll
        for (int d = 0; d < DD; ++d) acc += cp[d * JJ] * s_gamma[d];
        s_off[tid] = acc;
    }
    __syncthreads();

    if (tid < 3) {
        float sa = 0.f;
        for (int m = 0; m < MM; ++m) sa += s_sa[m * 3 + tid];
        s_SA[tid] = sa;
        float c = 0.f;
        for (int n = 0; n < NN; ++n) c += s_oa[n * 3 + tid];
        s_c[tid] = c * (1.0f / NN);
        float so = 0.f;
        for (int n = 0; n < NN; ++n) so += s_off[n * 3 + tid];
        s_sumoff[tid] = so;
    }
    __syncthreads();

    if (tid < 9) {
        int i = tid / 3, j = tid % 3;
        float cj = s_c[j];
        float h = 0.f;
        for (int n = 0; n < NN; ++n)
            h += s_off[n * 3 + i] * (s_oa[n * 3 + j] - cj);
        s_H[tid] = h;
    }
    __syncthreads();

    if (tid == 0) {
        // Horn's quaternion method: nearest SO(3) to H == U diag(1,1,det(UV^T)) V^T
        double H00 = s_H[0], H01 = s_H[1], H02 = s_H[2];
        double H10 = s_H[3], H11 = s_H[4], H12 = s_H[5];
        double H20 = s_H[6], H21 = s_H[7], H22 = s_H[8];

        double A[4][4], Vm[4][4];
        A[0][0] =  H00 + H11 + H22;
        A[1][1] =  H00 - H11 - H22;
        A[2][2] = -H00 + H11 - H22;
        A[3][3] = -H00 - H11 + H22;
        A[0][1] = A[1][0] = H21 - H12;
        A[0][2] = A[2][0] = H02 - H20;
        A[0][3] = A[3][0] = H10 - H01;
        A[1][2] = A[2][1] = H01 + H10;
        A[1][3] = A[3][1] = H02 + H20;
        A[2][3] = A[3][2] = H12 + H21;
        for (int r = 0; r < 4; ++r)
            for (int c2 = 0; c2 < 4; ++c2) Vm[r][c2] = (r == c2) ? 1.0 : 0.0;

        for (int sweep = 0; sweep < 10; ++sweep) {
            for (int p = 0; p < 3; ++p) {
                for (int q = p + 1; q < 4; ++q) {
                    double apq = A[p][q];
                    if (fabs(apq) < 1e-300) continue;
                    double tau = (A[q][q] - A[p][p]) / (2.0 * apq);
                    double tt  = (tau >= 0.0 ? 1.0 : -1.0) /
                                 (fabs(tau) + sqrt(1.0 + tau * tau));
                    double cc = 1.0 / sqrt(1.0 + tt * tt);
                    double ss = tt * cc;
                    for (int k = 0; k < 4; ++k) {
                        double akp = A[k][p], akq = A[k][q];
                        A[k][p] = cc * akp - ss * akq;
                        A[k][q] = ss * akp + cc * akq;
                    }
                    for (int k = 0; k < 4; ++k) {
                        double apk = A[p][k], aqk = A[q][k];
                        A[p][k] = cc * apk - ss * aqk;
                        A[q][k] = ss * apk + cc * aqk;
                    }
                    for (int k = 0; k < 4; ++k) {
                        double vkp = Vm[k][p], vkq = Vm[k][q];
                        Vm[k][p] = cc * vkp - ss * vkq;
                        Vm[k][q] = ss * vkp + cc * vkq;
                    }
                }
            }
        }
        int mi = 0;
        for (int i = 1; i < 4; ++i) if (A[i][i] > A[mi][mi]) mi = i;
        double w = Vm[0][mi], x = Vm[1][mi], y = Vm[2][mi], z = Vm[3][mi];
        double nrm = sqrt(w * w + x * x + y * y + z * z);
        w /= nrm; x /= nrm; y /= nrm; z /= nrm;

        double R[3][3];
        R[0][0] = w * w + x * x - y * y - z * z;
        R[0][1] = 2.0 * (x * y - w * z);
        R[0][2] = 2.0 * (x * z + w * y);
        R[1][0] = 2.0 * (x * y + w * z);
        R[1][1] = w * w - x * x + y * y - z * z;
        R[1][2] = 2.0 * (y * z - w * x);
        R[2][0] = 2.0 * (x * z - w * y);
        R[2][1] = 2.0 * (y * z + w * x);
        R[2][2] = w * w - x * x - y * y + z * z;

        float* Rout = out + (size_t)b * 9;
        for (int i = 0; i < 3; ++i)
            for (int j = 0; j < 3; ++j)
                Rout[i * 3 + j] = (float)R[i][j];

        float* Tout = out + (size_t)BB * 9 + (size_t)b * 3;
        for (int i = 0; i < 3; ++i) {
            double meanP = (double)s_SA[i] / (double)MM +
                           (double)s_sumoff[i] / (double)(MM * NN);
            double rc = R[i][0] * (double)s_c[0] + R[i][1] * (double)s_c[1] +
                        R[i][2] * (double)s_c[2];
            Tout[i] = (float)(meanP - rc);
        }
    }
}

extern "C" void kernel_launch(void* const* d_in, const int* in_sizes, int n_in,
                              void* d_out, int out_size, void* d_ws, size_t ws_size,
                              hipStream_t stream) {
    const float* gamma  = (const float*)d_in[0];
    const float* smpl_v = (const float*)d_in[1];
    const float* comps  = (const float*)d_in[2];
    const float* means  = (const float*)d_in[3];
    const float* oanch  = (const float*)d_in[4];
    const int*   labels = (const int*)d_in[5];
    const int*   sidx   = (const int*)d_in[6];
    float* out = (float*)d_out;

    float* Cred = (float*)d_ws;                       // 122880 floats
    float* Mred = Cred + NOBJ * DD * JJ;              // 3840 floats

    const int total = NOBJ * DD * JJ + NOBJ * JJ;     // 126720
    reduce_pca<<<(total + 255) / 256, 256, 0, stream>>>(comps, means, Cred, Mred);
    per_batch<<<BB, JJ, 0, stream>>>(gamma, smpl_v, oanch, labels, sidx,
                                     Cred, Mred, out);
}

// Round 5
// 147.469 us; speedup vs baseline: 1.4506x; 1.4506x over previous
//
#include <hip/hip_runtime.h>
#include <math.h>

// Problem constants
#define BB   1024
#define MM   32
#define NN   64
#define DD   32
#define NOBJ 20
#define NV   6890
#define KK   6144      // M*N*3
#define JJ   192       // N*3

// ---------------------------------------------------------------------------
// Kernel 1: reduce pca_components / pca_means over m (sum of M=32 strided
// rows), float4-vectorized. Cred[od*192 + j] = sum_m comps[od][m*192 + j]
// ---------------------------------------------------------------------------
__global__ void reduce_pca(const float* __restrict__ comps,
                           const float* __restrict__ means,
                           float* __restrict__ Cred,
                           float* __restrict__ Mred) {
    int t = blockIdx.x * blockDim.x + threadIdx.x;
    const int NC4 = NOBJ * DD * 48;          // 30720 float4 chunks for Cred
    if (t < NC4) {
        int jv = t % 48;
        int od = t / 48;                     // o*D + d
        const float4* p = reinterpret_cast<const float4*>(
            comps + (size_t)od * KK + jv * 4);
        float4 s = make_float4(0.f, 0.f, 0.f, 0.f);
#pragma unroll
        for (int m = 0; m < MM; ++m) {
            float4 v = p[m * 48];            // stride 192 floats
            s.x += v.x; s.y += v.y; s.z += v.z; s.w += v.w;
        }
        reinterpret_cast<float4*>(Cred)[t] = s;
    } else {
        int t2 = t - NC4;
        if (t2 < NOBJ * 48) {
            int jv = t2 % 48;
            int o  = t2 / 48;
            const float4* p = reinterpret_cast<const float4*>(
                means + (size_t)o * KK + jv * 4);
            float4 s = make_float4(0.f, 0.f, 0.f, 0.f);
#pragma unroll
            for (int m = 0; m < MM; ++m) {
                float4 v = p[m * 48];
                s.x += v.x; s.y += v.y; s.z += v.z; s.w += v.w;
            }
            reinterpret_cast<float4*>(Mred)[t2] = s;
        }
    }
}

// ---------------------------------------------------------------------------
// Kernel 2: one block (192 threads) per batch element. Computes H (3x3),
// center c (3), meanP (3) and stores 16 floats per batch into Hc.
// ---------------------------------------------------------------------------
__global__ __launch_bounds__(192) void per_batch_H(
    const float* __restrict__ gamma,    // [B,32]
    const float* __restrict__ smpl_v,   // [B,NV,3]
    const float* __restrict__ oanch,    // [NOBJ,64,3]
    const int*   __restrict__ labels,   // [B]
    const int*   __restrict__ sidx,     // [32]
    const float* __restrict__ Cred,     // [NOBJ, D, 192]
    const float* __restrict__ Mred,     // [NOBJ, 192]
    float* __restrict__ Hc)             // [B,16]: H(9), c(3), meanP(3), pad
{
    const int b   = blockIdx.x;
    const int tid = threadIdx.x;

    __shared__ float s_gamma[DD];
    __shared__ float s_oa[JJ];
    __shared__ float s_off[JJ];
    __shared__ float s_sa[MM * 3];
    __shared__ float s_SA[3], s_c[3], s_sumoff[3];

    const int o = labels[b];

    if (tid < DD) s_gamma[tid] = gamma[b * DD + tid];
    if (tid < MM * 3) {
        int m = tid / 3, i = tid % 3;
        int v = sidx[m];
        s_sa[tid] = smpl_v[((size_t)b * NV + v) * 3 + i];
    }
    s_oa[tid] = oanch[o * JJ + tid];    // blockDim == 192 == JJ
    __syncthreads();

    // OffSum[j] = Mred[o][j] + sum_d Cred[o][d][j] * gamma[d]
    {
        float acc = Mred[o * JJ + tid];
        const float* cp = Cred + (size_t)o * DD * JJ + tid;
#pragma unroll
        for (int d = 0; d < DD; ++d) acc += cp[d * JJ] * s_gamma[d];
        s_off[tid] = acc;
    }
    __syncthreads();

    if (tid < 3) {
        float sa = 0.f;
        for (int m = 0; m < MM; ++m) sa += s_sa[m * 3 + tid];
        s_SA[tid] = sa;
        float c = 0.f;
        for (int n = 0; n < NN; ++n) c += s_oa[n * 3 + tid];
        s_c[tid] = c * (1.0f / NN);
        float so = 0.f;
        for (int n = 0; n < NN; ++n) so += s_off[n * 3 + tid];
        s_sumoff[tid] = so;
    }
    __syncthreads();

    if (tid < 9) {
        int i = tid / 3, j = tid % 3;
        float cj = s_c[j];
        float h = 0.f;
        for (int n = 0; n < NN; ++n)
            h += s_off[n * 3 + i] * (s_oa[n * 3 + j] - cj);
        Hc[(size_t)b * 16 + tid] = h;
    }
    if (tid >= 9 && tid < 12) {
        Hc[(size_t)b * 16 + tid] = s_c[tid - 9];
    }
    if (tid >= 12 && tid < 15) {
        int i = tid - 12;
        Hc[(size_t)b * 16 + tid] =
            s_SA[i] * (1.0f / MM) + s_sumoff[i] * (1.0f / (MM * NN));
    }
}

// ---------------------------------------------------------------------------
// Kernel 3: one LANE per batch. f32 branchless cyclic Jacobi on Horn's 4x4
// K-matrix -> max eigenvector -> quaternion -> R, then T. 1024 lanes total.
// ---------------------------------------------------------------------------
__global__ __launch_bounds__(64) void solve(
    const float* __restrict__ Hc,       // [B,16]
    float* __restrict__ out)            // R flat [B*9] then T flat [B*3]
{
    const int b = blockIdx.x * 64 + threadIdx.x;
    const float* h = Hc + (size_t)b * 16;

    const float H00 = h[0], H01 = h[1], H02 = h[2];
    const float H10 = h[3], H11 = h[4], H12 = h[5];
    const float H20 = h[6], H21 = h[7], H22 = h[8];
    const float c0  = h[9], c1  = h[10], c2 = h[11];
    const float mP0 = h[12], mP1 = h[13], mP2 = h[14];

    float A[4][4], V[4][4];
    A[0][0] =  H00 + H11 + H22;
    A[1][1] =  H00 - H11 - H22;
    A[2][2] = -H00 + H11 - H22;
    A[3][3] = -H00 - H11 + H22;
    A[0][1] = A[1][0] = H21 - H12;
    A[0][2] = A[2][0] = H02 - H20;
    A[0][3] = A[3][0] = H10 - H01;
    A[1][2] = A[2][1] = H01 + H10;
    A[1][3] = A[3][1] = H02 + H20;
    A[2][3] = A[3][2] = H12 + H21;
#pragma unroll
    for (int r = 0; r < 4; ++r)
#pragma unroll
        for (int cc2 = 0; cc2 < 4; ++cc2) V[r][cc2] = (r == cc2) ? 1.f : 0.f;

    for (int sweep = 0; sweep < 8; ++sweep) {
#pragma unroll
        for (int p = 0; p < 3; ++p) {
#pragma unroll
            for (int q = p + 1; q < 4; ++q) {
                float apq  = A[p][q];
                float diff = A[q][q] - A[p][p];
                float sd   = (diff >= 0.f) ? 1.f : -1.f;
                // t = sgn(tau)/(|tau|+sqrt(1+tau^2)), tau = diff/(2 apq),
                // rewritten to avoid division by small apq:
                float tt = 2.f * apq * sd /
                           (fabsf(diff) + sqrtf(diff * diff + 4.f * apq * apq)
                            + 1e-30f);
                float cc = 1.f / sqrtf(1.f + tt * tt);
                float ss = tt * cc;
#pragma unroll
                for (int k = 0; k < 4; ++k) {
                    float akp = A[k][p], akq = A[k][q];
                    A[k][p] = cc * akp - ss * akq;
                    A[k][q] = ss * akp + cc * akq;
                }
#pragma unroll
                for (int k = 0; k < 4; ++k) {
                    float apk = A[p][k], aqk = A[q][k];
                    A[p][k] = cc * apk - ss * aqk;
                    A[q][k] = ss * apk + cc * aqk;
                }
#pragma unroll
                for (int k = 0; k < 4; ++k) {
                    float vkp = V[k][p], vkq = V[k][q];
                    V[k][p] = cc * vkp - ss * vkq;
                    V[k][q] = ss * vkp + cc * vkq;
                }
            }
        }
    }

    // Branchless max-diagonal selection (indices compile-time -> registers)
    float best = A[0][0];
    float w = V[0][0], x = V[1][0], y = V[2][0], z = V[3][0];
#pragma unroll
    for (int i = 1; i < 4; ++i) {
        bool gt = A[i][i] > best;
        best = gt ? A[i][i] : best;
        w = gt ? V[0][i] : w;
        x = gt ? V[1][i] : x;
        y = gt ? V[2][i] : y;
        z = gt ? V[3][i] : z;
    }
    float inv = 1.f / sqrtf(w * w + x * x + y * y + z * z);
    w *= inv; x *= inv; y *= inv; z *= inv;

    float R00 = w * w + x * x - y * y - z * z;
    float R01 = 2.f * (x * y - w * z);
    float R02 = 2.f * (x * z + w * y);
    float R10 = 2.f * (x * y + w * z);
    float R11 = w * w - x * x + y * y - z * z;
    float R12 = 2.f * (y * z - w * x);
    float R20 = 2.f * (x * z - w * y);
    float R21 = 2.f * (y * z + w * x);
    float R22 = w * w - x * x - y * y + z * z;

    float* Rout = out + (size_t)b * 9;
    Rout[0] = R00; Rout[1] = R01; Rout[2] = R02;
    Rout[3] = R10; Rout[4] = R11; Rout[5] = R12;
    Rout[6] = R20; Rout[7] = R21; Rout[8] = R22;

    float* Tout = out + (size_t)BB * 9 + (size_t)b * 3;
    Tout[0] = mP0 - (R00 * c0 + R01 * c1 + R02 * c2);
    Tout[1] = mP1 - (R10 * c0 + R11 * c1 + R12 * c2);
    Tout[2] = mP2 - (R20 * c0 + R21 * c1 + R22 * c2);
}

extern "C" void kernel_launch(void* const* d_in, const int* in_sizes, int n_in,
                              void* d_out, int out_size, void* d_ws, size_t ws_size,
                              hipStream_t stream) {
    const float* gamma  = (const float*)d_in[0];
    const float* smpl_v = (const float*)d_in[1];
    const float* comps  = (const float*)d_in[2];
    const float* means  = (const float*)d_in[3];
    const float* oanch  = (const float*)d_in[4];
    const int*   labels = (const int*)d_in[5];
    const int*   sidx   = (const int*)d_in[6];
    float* out = (float*)d_out;

    float* Cred = (float*)d_ws;                       // 122880 floats
    float* Mred = Cred + NOBJ * DD * JJ;              // 3840 floats
    float* Hc   = Mred + NOBJ * JJ;                   // 16384 floats

    const int total4 = NOBJ * DD * 48 + NOBJ * 48;    // 31680 float4 tasks
    reduce_pca<<<(total4 + 255) / 256, 256, 0, stream>>>(comps, means, Cred, Mred);
    per_batch_H<<<BB, JJ, 0, stream>>>(gamma, smpl_v, oanch, labels, sidx,
                                       Cred, Mred, Hc);
    solve<<<16, 64, 0, stream>>>(Hc, out);
}